// Round 7
// baseline (65.199 us; speedup 1.0000x reference)
//
#include <hip/hip_runtime.h>
#include <hip/hip_bf16.h>

// ScatterHorizontal round 7: h-split -> 2048 blocks (2 per batch), 2x parallelism.
// Shift d=i-4 is horizontal only, so h-rows split cleanly (no halo, no extra HBM).
// Block (b, hh): pixels p' = h0w + pp, pp in [0,npx), npx = 45 (h<5) or 36 (h>=5).
// Per block: 4 waves = 4 o-tiles of 16; M-tile 48 (3 m-frags); K=64 (2 k-frags).
// LDS [pixel][c] bf16 rows (136 B stride), double-buffered + zero row 45;
// reg-staged issue-early/write-late, 1 barrier/iter (R5/R6 structure).
// out[b,o,h,w'] = sum_i [0<=w'-d_i<9]( sum_c W[i,o,c]*x_i[b,c,h,w'-d_i] + bias[i,o] )

#define CIN   64
#define COUT  64
#define NOFF  9
#define HW    81
#define SLAB  5184           // f32 per (b,i) slab
#define RSTB  136            // LDS row stride bytes (64 bf16 = 128 + 8 pad)
#define NROW  46             // rows 0..44 data (max), row 45 = zero row
#define ZR    45
#define BUFB  (NROW * RSTB)  // 6256 B per buffer

typedef short bf16x8 __attribute__((ext_vector_type(8)));
typedef float f32x4  __attribute__((ext_vector_type(4)));

static __device__ __forceinline__ unsigned int f2bf(float v) {
    union { __hip_bfloat16 h; unsigned short u; } cv;
    cv.h = __float2bfloat16(v);
    return (unsigned int)cv.u;
}

// wfrag flat idx = (((i*2 + kt)*4 + ot)*64 + lane)*8 + j
//   value = bf16( W[i][o = 16*ot + (lane&15)][c = 32*kt + 8*(lane>>4) + j] )
__global__ __launch_bounds__(256) void prep_kernel(
    const float* __restrict__ wts,   // [9][64][64] (i,o,c)
    const float* __restrict__ bias,  // [9][64]
    unsigned short* __restrict__ wfrag,
    float* __restrict__ biasEff)     // [9][64] (w,o)
{
    int tid = blockIdx.x * 256 + threadIdx.x;
    int stride = gridDim.x * 256;
    for (int e = tid; e < NOFF * 4096; e += stride) {
        int j  = e & 7;
        int l  = (e >> 3) & 63;
        int ot = (e >> 9) & 3;
        int kt = (e >> 11) & 1;
        int i  = e >> 12;
        int o  = ot * 16 + (l & 15);
        int c  = kt * 32 + (l >> 4) * 8 + j;
        wfrag[e] = (unsigned short)f2bf(wts[(i * COUT + o) * CIN + c]);
    }
    if (blockIdx.x == 0) {
        for (int e = threadIdx.x; e < 9 * COUT; e += 256) {
            int w = e / COUT, o = e - w * COUT;
            int lo = (w - 4 > 0) ? (w - 4) : 0;
            int hi = (w + 4 < 8) ? (w + 4) : 8;
            float s = 0.f;
            for (int i2 = lo; i2 <= hi; ++i2) s += bias[i2 * COUT + o];
            biasEff[e] = s;
        }
    }
}

__global__ __launch_bounds__(256, 6) void scatter_mfma6_kernel(
    const float* __restrict__ x0, const float* __restrict__ x1,
    const float* __restrict__ x2, const float* __restrict__ x3,
    const float* __restrict__ x4, const float* __restrict__ x5,
    const float* __restrict__ x6, const float* __restrict__ x7,
    const float* __restrict__ x8,
    const unsigned short* __restrict__ wfrag,
    const float* __restrict__ biasEff,
    float* __restrict__ out)
{
    __shared__ __align__(16) unsigned char xs[2 * BUFB];   // 12512 B

    const int bid  = blockIdx.x;
    const int b    = bid >> 1;
    const int hh   = bid & 1;
    const int npx  = hh ? 36 : 45;    // pixels this block owns
    const int h0w  = hh ? 45 : 0;     // global pixel offset (= h0 * 9)
    const int t    = threadIdx.x;
    const int wid  = t >> 6;          // wave = o-tile (0..3)
    const int lane = t & 63;
    const int l15  = lane & 15;
    const int lhi  = lane >> 4;       // 0..3
    const int ocol = wid * 16 + l15;

    const float* xp[NOFF] = { x0, x1, x2, x3, x4, x5, x6, x7, x8 };

    // ---- staging map (i-invariant): chunk e = q*npx + px, e = t + 256k ----
    // chunk = (c-quad q in [0,16), pixel px); 4 dword loads stride 81,
    // one ds_write_b64 at row px, byte q*8.
    int goffk[3], wbytek[3];
    bool actk[3];
    {
        const int nchunk = npx * 16;   // 720 or 576
#pragma unroll
        for (int k = 0; k < 3; ++k) {
            int e = t + 256 * k;
            actk[k] = (e < nchunk);
            int ec = actk[k] ? e : 0;
            int q  = ec / npx;          // runtime div, once per kernel
            int px = ec - q * npx;
            goffk[k]  = q * 324 + px;   // dword offset within (slab + h0w)
            wbytek[k] = px * RSTB + q * 8;
        }
    }

    // A-row constants (i-invariant): m row = pp = mt*16 + l15
    int pAv[3], wAv[3];
#pragma unroll
    for (int mt = 0; mt < 3; ++mt) {
        pAv[mt] = mt * 16 + l15;
        wAv[mt] = (h0w + pAv[mt]) % 9;   // == pAv % 9 since h0w % 9 == 0
    }

    // accumulators init = biasEff[w'][o]
    f32x4 acc[3];
#pragma unroll
    for (int mt = 0; mt < 3; ++mt) {
#pragma unroll
        for (int jj = 0; jj < 4; ++jj) {
            int pp = mt * 16 + lhi * 4 + jj;   // pp <= 47; garbage rows unstored
            acc[mt][jj] = biasEff[(pp % 9) * COUT + ocol];
        }
    }

    // zero row ZR of both buffers (68 dwords)
    if (t < 68) {
        int idx = (t < 34) ? (ZR * RSTB + 4 * t)
                           : (BUFB + ZR * RSTB + 4 * (t - 34));
        *(unsigned int*)&xs[idx] = 0u;
    }

    // ---- prologue: stage slab 0 -> buf 0 ----
    {
        const float* src = xp[0] + (size_t)b * SLAB + h0w;
#pragma unroll
        for (int k = 0; k < 3; ++k) {
            if (actk[k]) {
                const float* sp = src + goffk[k];
                float c0 = sp[0], c1 = sp[81], c2 = sp[162], c3 = sp[243];
                uint2 v;
                v.x = f2bf(c0) | (f2bf(c1) << 16);
                v.y = f2bf(c2) | (f2bf(c3) << 16);
                *(uint2*)&xs[wbytek[k]] = v;
            }
        }
    }
    asm volatile("s_waitcnt lgkmcnt(0)" ::: "memory");
    __builtin_amdgcn_s_barrier();
    __builtin_amdgcn_sched_barrier(0);

#pragma unroll
    for (int i = 0; i < NOFF; ++i) {
        const unsigned char* bufR = &xs[(i & 1) * BUFB];

        // 1) B fragments for this offset (vector loads; wfrag L2-hot)
        bf16x8 bw[2];
#pragma unroll
        for (int kt = 0; kt < 2; ++kt)
            bw[kt] = *(const bf16x8*)&wfrag[(((i * 2 + kt) * 4 + wid) * 64 + lane) * 8];

        // 2) issue stage loads for slab i+1 (latency hides under DS+MFMA phase)
        float sf[3][4];
        if (i + 1 < NOFF) {
            const float* src = xp[i + 1] + (size_t)b * SLAB + h0w;
#pragma unroll
            for (int k = 0; k < 3; ++k) {
                if (actk[k]) {
                    const float* sp = src + goffk[k];
                    sf[k][0] = sp[0];   sf[k][1] = sp[81];
                    sf[k][2] = sp[162]; sf[k][3] = sp[243];
                }
            }
        }

        // 3) A-frag reads (12 x ds_read_b64) + 6 MFMA
        const int d = i - 4;
#pragma unroll
        for (int mt = 0; mt < 3; ++mt) {
            const bool valid = (unsigned)(wAv[mt] - d) < 9u;
            int q = valid ? (pAv[mt] - d) : ZR;   // valid lanes: q in [0,npx)
            if (q > ZR) q = ZR;                   // garbage rows: clamp in-bounds
            const unsigned char* rp = bufR + q * RSTB + lhi * 16;

#pragma unroll
            for (int kt = 0; kt < 2; ++kt) {
                int2 lo = *(const int2*)(rp + kt * 64);
                int2 hi = *(const int2*)(rp + kt * 64 + 8);
                int4 ai = { lo.x, lo.y, hi.x, hi.y };
                bf16x8 af = __builtin_bit_cast(bf16x8, ai);
                acc[mt] = __builtin_amdgcn_mfma_f32_16x16x32_bf16(af, bw[kt], acc[mt], 0, 0, 0);
            }
        }

        // 4) cvt + ds_write slab i+1 into the other buffer; 5) barrier
        if (i + 1 < NOFF) {
            unsigned char* bufW = &xs[((i + 1) & 1) * BUFB];
#pragma unroll
            for (int k = 0; k < 3; ++k) {
                if (actk[k]) {
                    uint2 v;
                    v.x = f2bf(sf[k][0]) | (f2bf(sf[k][1]) << 16);
                    v.y = f2bf(sf[k][2]) | (f2bf(sf[k][3]) << 16);
                    *(uint2*)(bufW + wbytek[k]) = v;
                }
            }
            asm volatile("s_waitcnt lgkmcnt(0)" ::: "memory");
            __builtin_amdgcn_s_barrier();
            __builtin_amdgcn_sched_barrier(0);
        }
    }

    // store: out[b, ocol, p' = h0w + pp] for pp < npx
    float* ob = out + (size_t)b * COUT * HW + (size_t)ocol * HW + h0w;
#pragma unroll
    for (int mt = 0; mt < 3; ++mt) {
#pragma unroll
        for (int jj = 0; jj < 4; ++jj) {
            const int pp = mt * 16 + lhi * 4 + jj;
            if (pp < npx) ob[pp] = acc[mt][jj];
        }
    }
}

extern "C" void kernel_launch(void* const* d_in, const int* in_sizes, int n_in,
                              void* d_out, int out_size, void* d_ws, size_t ws_size,
                              hipStream_t stream) {
    const float* x[9];
    for (int i = 0; i < 9; ++i) x[i] = (const float*)d_in[i];
    const float* wts  = (const float*)d_in[9];
    const float* bias = (const float*)d_in[10];
    float* out = (float*)d_out;

    unsigned short* wfrag = (unsigned short*)d_ws;                    // 73728 B
    float* biasEff = (float*)((char*)d_ws + NOFF * 4096 * sizeof(unsigned short));

    prep_kernel<<<144, 256, 0, stream>>>(wts, bias, wfrag, biasEff);
    scatter_mfma6_kernel<<<2048, 256, 0, stream>>>(
        x[0], x[1], x[2], x[3], x[4], x[5], x[6], x[7], x[8],
        wfrag, biasEff, out);
}